// Round 6
// baseline (59.774 us; speedup 1.0000x reference)
//
#include <hip/hip_runtime.h>
#include <hip/hip_bf16.h>

// ---------------------------------------------------------------------------
// PGAConjugateLinear as bf16 MFMA GEMM + bias.
//   out[b, n=o*3+p] = sum_{k=i*3+r} A[b][k] * Bw[n][k]  +  bias[n]
//   A[b][k]  = bf16(x[b][k])              (x is (4096,512,3) contiguous)
//   Bw[n][k] = weight[o,i] * T_oi[p][r]   (bf16, B^T layout, r in 0..2)
//   bias[n]  = sum_i weight[o,i] * T_oi[p][3] * e0[i]
// GEMM: M=4096, N=1536, K=1536. Tile 128x96, BK=32, 8 waves (4x2, 32x48
// each), grid 512 = exactly 2 blocks/CU, XCD-chunked.
// T3+T4 pipeline: TRIPLE-buffered LDS, depth-2 prefetch, raw s_barrier,
// counted s_waitcnt vmcnt(W) (never 0 in-loop). LDS stripe-transpose layout
// (slot = g*8 + (row&7) within 8-row stripes) -> conflict-free ds_read_b128,
// with linear global_load_lds dest + inverse-permuted global source.
// ---------------------------------------------------------------------------

#define B_DIM 4096
#define I_DIM 512
#define O_DIM 512
#define N_DIM (O_DIM * 3)   // 1536
#define K_DIM (I_DIM * 3)   // 1536
#define BK 32
#define NT (K_DIM / BK)     // 48 K-steps

typedef __attribute__((ext_vector_type(8))) short bf16x8;
typedef __attribute__((ext_vector_type(4))) float f32x4;

__device__ __forceinline__ unsigned short f2bf(float f) {
    unsigned u = __float_as_uint(f);
    unsigned r = (u + 0x7fffu + ((u >> 16) & 1u)) >> 16;  // RNE
    return (unsigned short)r;
}

__device__ __forceinline__ void gload_lds16(const void* g, void* l) {
    __builtin_amdgcn_global_load_lds(
        (const __attribute__((address_space(1))) unsigned*)g,
        (__attribute__((address_space(3))) unsigned*)l, 16, 0, 0);
}

// Cayley table for Cl(3,0,1), metric [0,1,1,1], reference blade order.
struct Cayley {
    float M[16][16][16];
    float rev[16];
    constexpr Cayley() : M{}, rev{} {
        const unsigned masks[16] = {0u, 1u, 2u, 4u, 8u, 3u, 5u, 9u, 6u, 10u,
                                    12u, 7u, 11u, 13u, 14u, 15u};
        int idx_of[16] = {};
        for (int i = 0; i < 16; ++i) idx_of[masks[i]] = i;
        const int metric[4] = {0, 1, 1, 1};
        for (int i = 0; i < 16; ++i) {
            unsigned a = masks[i];
            for (int j = 0; j < 16; ++j) {
                unsigned b = masks[j];
                int swaps = 0;
                for (int jb = 0; jb < 4; ++jb)
                    if ((b >> jb) & 1u)
                        for (int ia = jb + 1; ia < 4; ++ia)
                            if ((a >> ia) & 1u) ++swaps;
                int sign = (swaps & 1) ? -1 : 1;
                unsigned common = a & b;
                for (int g = 0; g < 4; ++g)
                    if ((common >> g) & 1u) sign *= metric[g];
                if (sign != 0) M[i][j][idx_of[a ^ b]] += (float)sign;
            }
            int grade = 0;
            for (int g = 0; g < 4; ++g) grade += (int)((a >> g) & 1u);
            rev[i] = ((grade * (grade - 1) / 2) % 2) ? -1.f : 1.f;
        }
    }
};
constexpr Cayley CAY{};

// ---------------------------------------------------------------------------
// prep: fused pack_x (blocks 0..1535) + build_w/bias (blocks 1536..2047).
// BW-bound pack blocks and VALU-bound build blocks co-schedule on CUs.
// ---------------------------------------------------------------------------
__global__ __launch_bounds__(512) void prep(const float* __restrict__ x,
                                            const float* __restrict__ weight,
                                            const float* __restrict__ action,
                                            const float* __restrict__ e0,
                                            unsigned short* __restrict__ A,
                                            unsigned short* __restrict__ Bw,
                                            float* __restrict__ bias) {
    const int bid = blockIdx.x;
    const int tid = threadIdx.x;

    if (bid < 1536) {
        // ---- pack: A = bf16(x), flat cast (k=i*3+r is exactly x's layout)
        const size_t t = (size_t)bid * 512 + tid;
        const float4* xp = (const float4*)(x + t * 8);
        const float4 v0 = xp[0], v1 = xp[1];
        const float xs[8] = {v0.x, v0.y, v0.z, v0.w, v1.x, v1.y, v1.z, v1.w};
        unsigned short ov[8];
#pragma unroll
        for (int q = 0; q < 8; ++q) ov[q] = f2bf(xs[q]);
        *(uint4*)(A + t * 8) = *(const uint4*)ov;   // 16B store
        return;
    }

    // ---- build: one block per o, one thread per i.
    const int o = bid - 1536;
    const int i = tid;
    const int t = o * I_DIM + i;
    const int wave = tid >> 6, lane = tid & 63;
    __shared__ float red[8][3];

    constexpr int AB[8] = {0, 5, 6, 7, 8, 9, 10, 15};
    constexpr int PB[3] = {11, 12, 13};
    constexpr int RB[4] = {11, 12, 13, 14};

    float a[8];
    const float* ap = action + (size_t)t * 8;
#pragma unroll
    for (int j = 0; j < 8; ++j) a[j] = ap[j];

    float kv[16], kr[16];
#pragma unroll
    for (int j = 0; j < 16; ++j) { kv[j] = 0.f; kr[j] = 0.f; }
#pragma unroll
    for (int j = 0; j < 8; ++j) {
        kv[AB[j]] = a[j];
        kr[AB[j]] = a[j] * CAY.rev[AB[j]];
    }

    float Am[3][16];
#pragma unroll
    for (int pp = 0; pp < 3; ++pp)
#pragma unroll
        for (int q = 0; q < 16; ++q) {
            float s = 0.f;
#pragma unroll
            for (int tt = 0; tt < 16; ++tt) s += CAY.M[q][PB[pp]][tt] * kr[tt];
            Am[pp][q] = s;
        }

    float Bm[16][4];
#pragma unroll
    for (int q = 0; q < 16; ++q)
#pragma unroll
        for (int rr = 0; rr < 4; ++rr) {
            float s = 0.f;
#pragma unroll
            for (int m = 0; m < 16; ++m) s += CAY.M[m][q][RB[rr]] * kv[m];
            Bm[q][rr] = s;
        }

    const float w = weight[t];
    const float e0i = e0[i];
    float sb[3];
#pragma unroll
    for (int pp = 0; pp < 3; ++pp) {
        float r0 = 0.f, r1 = 0.f, r2 = 0.f, r3 = 0.f;
#pragma unroll
        for (int q = 0; q < 16; ++q) {
            r0 += Am[pp][q] * Bm[q][0];
            r1 += Am[pp][q] * Bm[q][1];
            r2 += Am[pp][q] * Bm[q][2];
            r3 += Am[pp][q] * Bm[q][3];
        }
        unsigned short* bp = Bw + (size_t)(o * 3 + pp) * K_DIM + i * 3;
        bp[0] = f2bf(w * r0);
        bp[1] = f2bf(w * r1);
        bp[2] = f2bf(w * r2);
        sb[pp] = w * r3 * e0i;
    }

#pragma unroll
    for (int off = 32; off; off >>= 1) {
#pragma unroll
        for (int pp = 0; pp < 3; ++pp) sb[pp] += __shfl_down(sb[pp], off, 64);
    }
    if (lane == 0) {
#pragma unroll
        for (int pp = 0; pp < 3; ++pp) red[wave][pp] = sb[pp];
    }
    __syncthreads();
    if (tid == 0) {
#pragma unroll
        for (int pp = 0; pp < 3; ++pp) {
            float s = 0.f;
#pragma unroll
            for (int wv = 0; wv < 8; ++wv) s += red[wv][pp];
            bias[o * 3 + pp] = s;
        }
    }
}

// ---------------------------------------------------------------------------
// gemm: C[m][n] = sum_k A[m][k]*Bw[n][k] + bias[n].
// LDS layout per tile: 8-row stripes; slot(row, g) = (row>>3)*32 + g*8 + (row&7)
// (g = 16B col-seg, 4 per row at BK=32). ds_read_b128 of 64 lanes touches 64
// distinct slots -> 2-way bank aliasing (free). global_load_lds dest is
// linear slot=tid; source is the inverse permutation.
// Pipeline: 3 buffers; at step t: wait own tile-t loads (vmcnt W, tile t+1
// stays in flight), barrier, compute buf[t%3], stage tile t+2 into
// buf[(t+2)%3] (= buf computed at t-1; all waves passed this step's barrier
// after completing compute(t-1), so the overwrite is safe).
// ---------------------------------------------------------------------------
__global__ __launch_bounds__(512, 4) void gemm_bf16(
        const unsigned short* __restrict__ A,
        const unsigned short* __restrict__ Bw,
        const float* __restrict__ bias,
        float* __restrict__ C) {
    __shared__ unsigned short As0[4096], As1[4096], As2[4096];  // 8 KB each
    __shared__ unsigned short Bs0[3072], Bs1[3072], Bs2[3072];  // 6 KB each

    const int tid = threadIdx.x;
    const int wave = tid >> 6, lane = tid & 63;

    // XCD-chunked bijective swizzle (512 % 8 == 0), nt-fastest in chunk.
    const int bid = blockIdx.x;
    const int swz = (bid & 7) * 64 + (bid >> 3);
    const int mt = swz >> 4, nt = swz & 15;
    const int m0 = mt * 128, n0 = nt * 96;
    const int wr = wave >> 1, wc = wave & 1;    // 4x2 wave grid, 32x48 each

    // staging sources (inverse of the stripe-transpose LDS layout):
    // LDS slot s=tid holds global (row=(s>>5)*8+(s&7), colseg=(s>>3)&3)
    const int arow = (tid >> 5) * 8 + (tid & 7);
    const int acs = (tid >> 3) & 3;
    const unsigned short* aSrc = A + (size_t)(m0 + arow) * K_DIM + acs * 8;
    const int brow = (tid >> 5) * 8 + (tid & 7);
    const int bcs = (tid >> 3) & 3;
    const unsigned short* bSrc = Bw + (size_t)(n0 + brow) * K_DIM + bcs * 8;
    const bool hasB = tid < 384;    // B: 384 segs (wave-uniform predicate)

    // fragment read offsets (shorts): slot(r, g0)*8
    const int frow = lane & 15;
    const int g0 = lane >> 4;
    int aro[2], bro[3];
#pragma unroll
    for (int mi = 0; mi < 2; ++mi) {
        const int r = wr * 32 + mi * 16 + frow;
        aro[mi] = ((r >> 3) * 32 + g0 * 8 + (r & 7)) * 8;
    }
#pragma unroll
    for (int ni = 0; ni < 3; ++ni) {
        const int r = wc * 48 + ni * 16 + frow;
        bro[ni] = ((r >> 3) * 32 + g0 * 8 + (r & 7)) * 8;
    }

    f32x4 acc[2][3] = {};

#define STAGE(AS, BS, T)                                     \
    do {                                                     \
        gload_lds16(aSrc + (T) * BK, (AS) + tid * 8);        \
        if (hasB) gload_lds16(bSrc + (T) * BK, (BS) + tid * 8); \
    } while (0)

#define COMPUTE(AS, BS)                                                   \
    do {                                                                  \
        bf16x8 af[2], bfr[3];                                             \
        _Pragma("unroll")                                                 \
        for (int mi = 0; mi < 2; ++mi)                                    \
            af[mi] = *(const bf16x8*)&(AS)[aro[mi]];                      \
        _Pragma("unroll")                                                 \
        for (int ni = 0; ni < 3; ++ni)                                    \
            bfr[ni] = *(const bf16x8*)&(BS)[bro[ni]];                     \
        _Pragma("unroll")                                                 \
        for (int mi = 0; mi < 2; ++mi)                                    \
            _Pragma("unroll")                                             \
            for (int ni = 0; ni < 3; ++ni)                                \
                acc[mi][ni] = __builtin_amdgcn_mfma_f32_16x16x32_bf16(    \
                    af[mi], bfr[ni], acc[mi][ni], 0, 0, 0);               \
    } while (0)

// wait own tile-t loads done (W per wave: 2 if it stages A+B, 1 if A only);
// tile t+1's loads remain in flight across the barrier (T4: never drain).
#define WAITW                                                      \
    do {                                                           \
        if (hasB) asm volatile("s_waitcnt vmcnt(2)" ::: "memory"); \
        else      asm volatile("s_waitcnt vmcnt(1)" ::: "memory"); \
        __builtin_amdgcn_s_barrier();                              \
    } while (0)
#define WAIT0                                                \
    do {                                                     \
        asm volatile("s_waitcnt vmcnt(0)" ::: "memory");     \
        __builtin_amdgcn_s_barrier();                        \
    } while (0)

    STAGE(As0, Bs0, 0);
    STAGE(As1, Bs1, 1);

#pragma unroll 1
    for (int u = 0; u < 15; ++u) {       // steps t = 3u, 3u+1, 3u+2 (0..44)
        const int t = u * 3;
        WAITW; COMPUTE(As0, Bs0); STAGE(As2, Bs2, t + 2);
        WAITW; COMPUTE(As1, Bs1); STAGE(As0, Bs0, t + 3);
        WAITW; COMPUTE(As2, Bs2); STAGE(As1, Bs1, t + 4);
    }
    // t = 45, 46, 47
    WAITW; COMPUTE(As0, Bs0); STAGE(As2, Bs2, 47);
    WAITW; COMPUTE(As1, Bs1);
    WAIT0; COMPUTE(As2, Bs2);

#undef STAGE
#undef COMPUTE
#undef WAITW
#undef WAIT0

    // epilogue: C/D layout col = lane&15, row = (lane>>4)*4 + j; add bias[n]
    const int crow = (lane >> 4) * 4;
    const int ccol = lane & 15;
#pragma unroll
    for (int mi = 0; mi < 2; ++mi)
#pragma unroll
        for (int ni = 0; ni < 3; ++ni) {
            const int n = n0 + wc * 48 + ni * 16 + ccol;
            const float bv = bias[n];
            float* cp = C + (size_t)(m0 + wr * 32 + mi * 16 + crow) * N_DIM + n;
#pragma unroll
            for (int j = 0; j < 4; ++j) cp[(size_t)j * N_DIM] = acc[mi][ni][j] + bv;
        }
}

// ---------------------------------------------------------------------------
extern "C" void kernel_launch(void* const* d_in, const int* in_sizes, int n_in,
                              void* d_out, int out_size, void* d_ws, size_t ws_size,
                              hipStream_t stream) {
    const float* x      = (const float*)d_in[0];  // (4096, 512, 3)
    const float* weight = (const float*)d_in[1];  // (512, 512)
    const float* action = (const float*)d_in[2];  // (512, 512, 8)
    const float* e0     = (const float*)d_in[3];  // (512, 1)
    float* out = (float*)d_out;                   // (4096, 512, 3)

    unsigned short* Bw = (unsigned short*)d_ws;                 // 4.7 MB
    unsigned short* Ap = Bw + (size_t)N_DIM * K_DIM;            // 12.6 MB
    float* bias = (float*)(Ap + (size_t)B_DIM * K_DIM);         // 1536 f32

    hipLaunchKernelGGL(prep, dim3(2048), dim3(512), 0, stream,
                       x, weight, action, e0, Ap, Bw, bias);
    hipLaunchKernelGGL(gemm_bf16, dim3(512), dim3(512), 0, stream,
                       Ap, Bw, bias, out);
}